// Round 5
// baseline (75.605 us; speedup 1.0000x reference)
//
#include <hip/hip_runtime.h>

#define NIMG 64
#define NUQ 6
#define NSTRIP 16
#define SROWS 32
#define HW (512 * 512)

// 8 reference offsets contain (1,1) and (1,-1) twice -> 6 unique, weighted.
__device__ __constant__ float UOFF_W[NUQ] = {1.f, 2.f, 1.f, 2.f, 1.f, 1.f};
// dr nibbles {0,1,1,1,0,2}; (dc+1) nibbles {2,2,1,0,3,1}
#define DR_PACK 0x201110u
#define DCP_PACK 0x130122u

__device__ __forceinline__ unsigned char quant1(float x, float y, float z) {
    float gray = (x + y + z) / 3.0f;
    float t = (gray + 1.0f) * 0.5f * 31.0f;
    t = fminf(fmaxf(t, 0.0f), 31.0f);
    return (unsigned char)(int)t;
}

// packed-u16 hist: dword d = (i<<4) | ((i + (j>>1)) & 15); half = j&1.
__device__ __forceinline__ void ppair(int i, int j, unsigned int* __restrict__ hu) {
    int d = (i << 4) | ((i + (j >> 1)) & 15);
    atomicAdd(&hu[d], 1u << ((j & 1) << 4));
}

// ---- Fused: per (image, 32-row strip); distance-2 pipelined quantize || hist ----
__global__ __launch_bounds__(256) void glcm_fused(
    const float* __restrict__ in, unsigned int* __restrict__ hist_g) {
    const int b = blockIdx.x >> 4;
    const int s = blockIdx.x & 15;
    const int rs = s * SROWS;

    __shared__ unsigned char ring[4 * 2048];   // 4 chunk slots x (4 rows x 512)
    __shared__ unsigned int hist[NUQ * 512];   // packed u16-pair bins, 12 KB

    const int tid = threadIdx.x;
    for (int k = tid; k < NUQ * 512; k += 256) hist[k] = 0;

    const float* ib = in + (size_t)b * (3 * HW);
    const int lrow = tid >> 6;            // row within chunk
    const int lcol = (tid & 63) << 3;     // 8 pixels per thread

    auto issueL = [&](int c, float4& A0, float4& B0, float4& A1, float4& B1,
                      float4& A2, float4& B2) {
        const int gr = rs + (c << 2) + lrow;
        if ((c << 2) + lrow < SROWS + 2 && gr < 512) {
            const float* p = ib + ((size_t)gr << 9) + lcol;
            A0 = *(const float4*)(p);
            B0 = *(const float4*)(p + 4);
            A1 = *(const float4*)(p + HW);
            B1 = *(const float4*)(p + HW + 4);
            A2 = *(const float4*)(p + 2 * HW);
            B2 = *(const float4*)(p + 2 * HW + 4);
        }
    };

    auto quantW = [&](int c, const float4& A0, const float4& B0, const float4& A1,
                      const float4& B1, const float4& A2, const float4& B2) {
        const int gr = rs + (c << 2) + lrow;
        if ((c << 2) + lrow < SROWS + 2 && gr < 512) {
            unsigned int q0 =
                (unsigned int)quant1(A0.x, A1.x, A2.x)
                | ((unsigned int)quant1(A0.y, A1.y, A2.y) << 8)
                | ((unsigned int)quant1(A0.z, A1.z, A2.z) << 16)
                | ((unsigned int)quant1(A0.w, A1.w, A2.w) << 24);
            unsigned int q1 =
                (unsigned int)quant1(B0.x, B1.x, B2.x)
                | ((unsigned int)quant1(B0.y, B1.y, B2.y) << 8)
                | ((unsigned int)quant1(B0.z, B1.z, B2.z) << 16)
                | ((unsigned int)quant1(B0.w, B1.w, B2.w) << 24);
            uint2* wp = (uint2*)(ring + ((c & 3) << 11) + (lrow << 9) + lcol);
            *wp = make_uint2(q0, q1);
        }
    };

    auto histF = [&](int k) {
        // main: 6 offsets x 4 rows x 32 full 16-px groups = 768 slots
        for (int idx = tid; idx < 768; idx += 256) {
            int u = idx >> 7;                       // wave-uniform
            int rem = idx & 127;
            int r4 = rem >> 5;
            int g = rem & 31;
            int dr = (DR_PACK >> (u << 2)) & 15;
            int dc = (int)((DCP_PACK >> (u << 2)) & 15) - 1;
            int R = (k << 2) + r4;
            int nr_u = min(512 - dr - rs, SROWS);
            int gA = (dc < 0) ? 1 : 0;
            int gEnd = (dc > 0) ? 31 : 32;
            if (R < nr_u && g >= gA && g < gEnd) {
                const uint4* ip = (const uint4*)(ring + ((k & 3) << 11) + (r4 << 9) + (g << 4));
                uint4 iw = *ip;
                int Rj = R + dr;
                int jbase = (((Rj >> 2) & 3) << 11) + ((Rj & 3) << 9);
                unsigned int jw0, jw1, jw2, jw3;
                if (dc == 0) {
                    uint4 jv = *(const uint4*)(ring + jbase + (g << 4));
                    jw0 = jv.x; jw1 = jv.y; jw2 = jv.z; jw3 = jv.w;
                } else {
                    int jb = jbase + (g << 4) + dc;
                    const unsigned int* t32 = (const unsigned int*)(ring + (jb & ~3));
                    int sb = (jb & 3) << 3;          // 8, 16 or 24 (never 0)
                    unsigned int w0 = t32[0], w1 = t32[1], w2 = t32[2],
                                 w3 = t32[3], w4 = t32[4];
                    jw0 = (w0 >> sb) | (w1 << (32 - sb));
                    jw1 = (w1 >> sb) | (w2 << (32 - sb));
                    jw2 = (w2 >> sb) | (w3 << (32 - sb));
                    jw3 = (w3 >> sb) | (w4 << (32 - sb));
                }
                unsigned int* hu = hist + (u << 9);
                #pragma unroll
                for (int q = 0; q < 4; ++q) {
                    ppair((iw.x >> (8 * q)) & 255, (jw0 >> (8 * q)) & 255, hu);
                    ppair((iw.y >> (8 * q)) & 255, (jw1 >> (8 * q)) & 255, hu);
                    ppair((iw.z >> (8 * q)) & 255, (jw2 >> (8 * q)) & 255, hu);
                    ppair((iw.w >> (8 * q)) & 255, (jw3 >> (8 * q)) & 255, hu);
                }
            }
        }
        // edges: 6 offsets x 4 rows x <=15 ragged cols = 384 slots
        for (int idx = tid; idx < 384; idx += 256) {
            int u = idx >> 6;                       // wave-uniform
            int rem = idx & 63;
            int r4 = rem >> 4;
            int e = rem & 15;
            int dr = (DR_PACK >> (u << 2)) & 15;
            int dc = (int)((DCP_PACK >> (u << 2)) & 15) - 1;
            int elen = (dc == 0) ? 0 : ((dc == 2) ? 14 : 15);
            int ebase = (dc < 0) ? 1 : 496;
            int R = (k << 2) + r4;
            int nr_u = min(512 - dr - rs, SROWS);
            if (e < elen && R < nr_u) {
                int ci = ebase + e;
                int ia = ((k & 3) << 11) + (r4 << 9) + ci;
                int Rj = R + dr;
                int ja = (((Rj >> 2) & 3) << 11) + ((Rj & 3) << 9) + ci + dc;
                ppair(ring[ia], ring[ja], hist + (u << 9));
            }
        }
    };

    // two statically-named register sets (A = even chunks, B = odd chunks)
    float4 zA0 = {0,0,0,0}, zB0 = {0,0,0,0}, zA1 = {0,0,0,0},
           zB1 = {0,0,0,0}, zA2 = {0,0,0,0}, zB2 = {0,0,0,0};
    float4 yA0 = {0,0,0,0}, yB0 = {0,0,0,0}, yA1 = {0,0,0,0},
           yB1 = {0,0,0,0}, yA2 = {0,0,0,0}, yB2 = {0,0,0,0};

    for (int cc = 0; cc < 12; cc += 2) {
        {   // even c: loads -> z-set, quantize consumes y-set (chunk c-1, odd)
            const int c = cc;
            if (c <= 8) issueL(c, zA0, zB0, zA1, zB1, zA2, zB2);
            if (c >= 3 && c <= 10) histF(c - 3);
            if (c >= 1 && c <= 9) quantW(c - 1, yA0, yB0, yA1, yB1, yA2, yB2);
            __syncthreads();
        }
        {   // odd c: loads -> y-set, quantize consumes z-set (chunk c-1, even)
            const int c = cc + 1;
            if (c <= 8) issueL(c, yA0, yB0, yA1, yB1, yA2, yB2);
            if (c >= 3 && c <= 10) histF(c - 3);
            if (c >= 1 && c <= 9) quantW(c - 1, zA0, zB0, zA1, zB1, zA2, zB2);
            __syncthreads();
        }
    }

    // flush packed strip-hist with plain stores (no memset, no atomics)
    unsigned int* hb = hist_g + (size_t)blockIdx.x * (NUQ * 512);
    for (int k = tid; k < NUQ * 512; k += 256) hb[k] = hist[k];
}

// ---- features + weighted offset average, one block per image ----
__global__ __launch_bounds__(256) void feature_out_kernel(
    const unsigned int* __restrict__ hist_g, float* __restrict__ out) {
    const int b = blockIdx.x;
    __shared__ unsigned int cnt[NUQ][1024];    // 24 KB
    __shared__ float fred[NUQ][4];
    const int tid = threadIdx.x;
    const int wid = tid >> 6;
    const int lane = tid & 63;

    // phase 1: per-wave strip-sum + unpack into cnt[u]
    for (int u = wid; u < NUQ; u += 4) {
        const unsigned int* p = hist_g + ((size_t)b * NSTRIP * NUQ + u) * 512;
        for (int d = lane; d < 512; d += 64) {
            unsigned int lo = 0, hi = 0;
            #pragma unroll
            for (int st = 0; st < NSTRIP; ++st) {
                unsigned int v = p[(size_t)st * NUQ * 512 + d];
                lo += v & 0xffffu;
                hi += v >> 16;
            }
            int i = d >> 4;
            int jh = ((d & 15) - i) & 15;
            cnt[u][(i << 5) | (jh << 1)] = lo;
            cnt[u][(i << 5) | (jh << 1) | 1] = hi;
        }
    }
    __syncthreads();

    // phase 2: per-wave moments over 1024 bins
    for (int u = wid; u < NUQ; u += 4) {
        int dr = (DR_PACK >> (u << 2)) & 15;
        int dc = (int)((DCP_PACK >> (u << 2)) & 15) - 1;
        int adc = dc < 0 ? -dc : dc;
        float inv_total = 1.0f / (2.0f * (float)((512 - dr) * (512 - adc)));
        float c_sum = 0.f, h_sum = 0.f, e_sum = 0.f, m1 = 0.f, m2 = 0.f, m12 = 0.f;
        for (int k = lane; k < 1024; k += 64) {
            int i = k >> 5, j = k & 31;
            float sym = (float)(cnt[u][k] + cnt[u][(j << 5) | i]);
            float P = sym * inv_total;
            float d = (float)(i - j);
            float d2 = d * d;
            float fi = (float)i, fj = (float)j;
            c_sum += P * d2;
            h_sum += P / (1.0f + d2);
            e_sum += P * P;
            m1  += P * fi;
            m2  += P * fi * fi;
            m12 += P * fi * fj;
        }
        #pragma unroll
        for (int sft = 32; sft > 0; sft >>= 1) {
            c_sum += __shfl_down(c_sum, sft);
            h_sum += __shfl_down(h_sum, sft);
            e_sum += __shfl_down(e_sum, sft);
            m1    += __shfl_down(m1, sft);
            m2    += __shfl_down(m2, sft);
            m12   += __shfl_down(m12, sft);
        }
        if (lane == 0) {
            float mu  = m1;
            float var = m2 - mu * mu;
            float cov = m12 - mu * mu;
            float corr = (var > 1e-15f) ? cov / var : 1.0f;   // std_i*std_j = var (P symmetric)
            fred[u][0] = c_sum;
            fred[u][1] = h_sum;
            fred[u][2] = sqrtf(e_sum);
            fred[u][3] = corr;
        }
    }
    __syncthreads();

    if (tid < 4) {
        float s = 0.f;
        #pragma unroll
        for (int u = 0; u < NUQ; ++u) s += UOFF_W[u] * fred[u][tid];
        out[tid * NIMG + b] = s * 0.125f;
    }
}

extern "C" void kernel_launch(void* const* d_in, const int* in_sizes, int n_in,
                              void* d_out, int out_size, void* d_ws, size_t ws_size,
                              hipStream_t stream) {
    const float* images = (const float*)d_in[0];
    float* out = (float*)d_out;

    unsigned int* hist_g = (unsigned int*)d_ws;   // 1024 blocks x 3072 u32 = 12.6 MB

    glcm_fused<<<NIMG * NSTRIP, 256, 0, stream>>>(images, hist_g);
    feature_out_kernel<<<NIMG, 256, 0, stream>>>(hist_g, out);
}

// Round 6
// 71.974 us; speedup vs baseline: 1.0504x; 1.0504x over previous
//
#include <hip/hip_runtime.h>

typedef unsigned int uint;

#define HW (512 * 512)
#define NIMG 64
#define NUQ 6
#define QSTRIDE 528
#define FLB 32768          // float ring base (2 slots x 12288)
#define QRB 57344          // quant ring base (8 rows x 528)
#define SMEM_BYTES 61568   // 32768 hist + 24576 float ring + 4224 quant ring

// offsets (all dc >= 0; (1,-1) reformulated as (-1,1), transpose-equivalent
// under the final P+P^T symmetrization):
// u0 (0,1)  w1 tag0 lo | u1 (1,1) w2 tag1 lo | u2 (1,0) w1 tag2 lo
// u3 (-1,1) w2 tag0 hi | u4 (0,2) w1 tag1 hi | u5 (2,0) w1 tag2 hi
__device__ __constant__ float UOFF_W[NUQ] = {1.f, 2.f, 1.f, 2.f, 1.f, 1.f};
__device__ __constant__ float NPAIRS[NUQ] = {
    512.f * 511.f, 511.f * 511.f, 511.f * 512.f,
    511.f * 511.f, 512.f * 510.f, 510.f * 512.f};

__device__ __forceinline__ uint q1f(float a, float b, float c) {
    // ((a+b+c)/3 + 1) * 0.5 * 31 == (a+b+c)*(31/6) + 15.5
    float t = fmaf(a + b + c, 5.1666665f, 15.5f);
    t = fminf(fmaxf(t, 0.0f), 31.0f);
    return (uint)t;                       // trunc, matches astype(int32)
}

__global__ __launch_bounds__(256) void glcm_fused(
    const float* __restrict__ in, uint* __restrict__ wire) {
    __shared__ __align__(16) unsigned char smem[SMEM_BYTES];
    const int tid = threadIdx.x;
    const int b = blockIdx.x >> 4;
    const int s = blockIdx.x & 15;
    const int rs = s * 32;
    const int w = tid >> 6;
    const int lane = tid & 63;
    const float* ib = in + (size_t)b * (3 * HW);

    // zero hist (32 KB, includes junk bins)
    {
        uint4 z = make_uint4(0, 0, 0, 0);
        #pragma unroll
        for (int q = 0; q < 8; ++q)
            *(uint4*)(smem + tid * 16 + q * 4096) = z;
    }

    // ---- async stage: chunk cc = 2 rows x 512 px x 3ch floats -> slot cc&1 ----
    auto issue = [&](int cc) {
        const int slot = cc & 1;
        const int R0 = rs - 2 + 2 * cc;
        #pragma unroll
        for (int ch = 0; ch < 3; ++ch) {
            int row = min(max(R0 + (w >> 1), 0), 511);   // clamp: garbage rows never read
            const float* src = ib + ch * HW + row * 512 + (w & 1) * 256 + lane * 4;
            __builtin_amdgcn_global_load_lds(
                (const __attribute__((address_space(1))) void*)src,
                (__attribute__((address_space(3))) void*)(smem + FLB + slot * 12288 + (ch * 4 + w) * 1024),
                16, 0, 0);
        }
    };

    issue(0);   // prologue

    for (int c = 0; c <= 18; ++c) {
        // (A) issue next chunk's HBM->LDS loads
        if (c + 1 <= 17) issue(c + 1);

        // (B) histogram chunk h = c-2 (pair rows rs-2+2h, +1) from quant ring
        const int h = c - 2;
        if (h >= 1 && h <= 16) {
            const int lr = tid >> 7;
            const int dq = tid & 127;
            const int R = rs - 2 + 2 * h + lr;
            const unsigned char* qr = smem + QRB;
            const uint* rowL   = (const uint*)(qr + ((R)     & 7) * QSTRIDE);
            const uint* rowLm  = (const uint*)(qr + ((R - 1) & 7) * QSTRIDE);
            const uint* rowLp  = (const uint*)(qr + ((R + 1) & 7) * QSTRIDE);
            const uint* rowLpp = (const uint*)(qr + ((R + 2) & 7) * QSTRIDE);
            uint A = rowL[dq],  A1 = rowL[dq + 1];       // dq=127 -> [128] = pad dword
            uint B = rowLp[dq], B1 = rowLp[dq + 1];
            uint C = rowLm[dq], C1 = rowLm[dq + 1];
            uint D = rowLpp[dq];

            auto pp4 = [&](uint jw, int tagoff, uint inc, int rlo, int rhi) {
                if (R >= rlo && R < rhi) {
                    // addr = (i<<10)|(j<<2): bytes are pre-shifted q<<2; pad 0x80 -> junk bin
                    uint a0 = __builtin_amdgcn_perm(A, jw, 0x0C0C0400u) & 0xFCFCu;
                    uint a1 = __builtin_amdgcn_perm(A, jw, 0x0C0C0501u) & 0xFCFCu;
                    uint a2 = __builtin_amdgcn_perm(A, jw, 0x0C0C0602u) & 0xFCFCu;
                    uint a3 = __builtin_amdgcn_perm(A, jw, 0x0C0C0703u) & 0xFCFCu;
                    atomicAdd((uint*)(smem + tagoff + a0), inc);
                    atomicAdd((uint*)(smem + tagoff + a1), inc);
                    atomicAdd((uint*)(smem + tagoff + a2), inc);
                    atomicAdd((uint*)(smem + tagoff + a3), inc);
                }
            };
            pp4(__builtin_amdgcn_alignbyte(A1, A, 1), 0,   1u,     0, 512);  // u0 (0,1)
            pp4(__builtin_amdgcn_alignbyte(B1, B, 1), 256, 1u,     0, 511);  // u1 (1,1)
            pp4(B,                                    512, 1u,     0, 511);  // u2 (1,0)
            pp4(__builtin_amdgcn_alignbyte(C1, C, 1), 0,   65536u, 1, 512);  // u3 (-1,1)
            pp4(__builtin_amdgcn_alignbyte(A1, A, 2), 256, 65536u, 0, 512);  // u4 (0,2)
            pp4(D,                                    512, 65536u, 0, 510);  // u5 (2,0)
        }

        // (C) barrier: drains chunk c's global_load_lds (syncthreads implies vmcnt(0))
        __syncthreads();

        // (D) quantize chunk c: floats (slot c&1) -> quant ring rows (pre-shifted <<2)
        if (c <= 17) {
            const int r = tid >> 7;
            const int c4 = (tid & 127) << 2;
            const int R = rs - 2 + 2 * c + r;
            const float* fb = (const float*)(smem + FLB + (c & 1) * 12288);
            float4 f0 = *(const float4*)(fb + 0 * 1024 + r * 512 + c4);
            float4 f1 = *(const float4*)(fb + 1 * 1024 + r * 512 + c4);
            float4 f2 = *(const float4*)(fb + 2 * 1024 + r * 512 + c4);
            uint q = (q1f(f0.x, f1.x, f2.x) << 2)
                   | (q1f(f0.y, f1.y, f2.y) << 10)
                   | (q1f(f0.z, f1.z, f2.z) << 18)
                   | (q1f(f0.w, f1.w, f2.w) << 26);
            unsigned char* qrw = smem + QRB + ((R) & 7) * QSTRIDE;
            *(uint*)(qrw + c4) = q;
            if ((tid & 127) == 127)   // sentinel pads, cols 512..527
                *(uint4*)(qrw + 512) =
                    make_uint4(0x80808080u, 0x80808080u, 0x80808080u, 0x80808080u);
        }

        // (E) barrier: quant ring visible to next hist; float slot safe to refill
        __syncthreads();
    }

    // ---- flush: compress 32 KB (valid bins only) -> 12 KB wire, plain stores ----
    uint* hb = wire + (size_t)blockIdx.x * 3072;
    const uint* hist = (const uint*)smem;
    #pragma unroll
    for (int qq = 0; qq < 12; ++qq) {
        int o = tid + qq * 256;          // o = tag*1024 + i*32 + j
        int tg = o >> 10, ij = o & 1023;
        int i = ij >> 5, j = ij & 31;
        hb[o] = hist[(i << 8) | (tg << 6) | j];
    }
}

// ---- features + weighted offset average, one block per image ----
__global__ __launch_bounds__(256) void feature_out_kernel(
    const uint* __restrict__ wire, float* __restrict__ out) {
    const int b = blockIdx.x;
    __shared__ uint cnt[NUQ][1024];      // 24 KB
    __shared__ float fred[NUQ][4];
    const int tid = threadIdx.x, wid = tid >> 6, lane = tid & 63;

    for (int u = wid; u < NUQ; u += 4) {
        const int tg = (u < 3) ? u : u - 3;
        const int sh = (u < 3) ? 0 : 16;
        const uint* p = wire + (size_t)b * (16 * 3072) + tg * 1024;
        for (int ij = lane; ij < 1024; ij += 64) {
            uint acc = 0;
            #pragma unroll
            for (int st = 0; st < 16; ++st)
                acc += (p[(size_t)st * 3072 + ij] >> sh) & 0xFFFFu;
            cnt[u][ij] = acc;
        }
    }
    __syncthreads();

    for (int u = wid; u < NUQ; u += 4) {
        const float inv_total = 1.0f / (2.0f * NPAIRS[u]);
        float c_sum = 0, h_sum = 0, e_sum = 0, m1 = 0, m2 = 0, m12 = 0;
        for (int k = lane; k < 1024; k += 64) {
            int i = k >> 5, j = k & 31;
            float sym = (float)(cnt[u][k] + cnt[u][(j << 5) | i]);
            float P = sym * inv_total;
            float d = (float)(i - j);
            float d2 = d * d;
            float fi = (float)i, fj = (float)j;
            c_sum += P * d2;
            h_sum += P / (1.0f + d2);
            e_sum += P * P;
            m1 += P * fi; m2 += P * fi * fi; m12 += P * fi * fj;
        }
        #pragma unroll
        for (int sft = 32; sft > 0; sft >>= 1) {
            c_sum += __shfl_down(c_sum, sft);
            h_sum += __shfl_down(h_sum, sft);
            e_sum += __shfl_down(e_sum, sft);
            m1 += __shfl_down(m1, sft);
            m2 += __shfl_down(m2, sft);
            m12 += __shfl_down(m12, sft);
        }
        if (lane == 0) {
            float mu = m1, var = m2 - mu * mu, cov = m12 - mu * mu;
            float corr = (var > 1e-15f) ? cov / var : 1.0f;  // std_i*std_j = var (P symmetric)
            fred[u][0] = c_sum; fred[u][1] = h_sum;
            fred[u][2] = sqrtf(e_sum); fred[u][3] = corr;
        }
    }
    __syncthreads();
    if (tid < 4) {
        float acc = 0.f;
        #pragma unroll
        for (int u = 0; u < NUQ; ++u) acc += UOFF_W[u] * fred[u][tid];
        out[tid * NIMG + b] = acc * 0.125f;
    }
}

extern "C" void kernel_launch(void* const* d_in, const int* in_sizes, int n_in,
                              void* d_out, int out_size, void* d_ws, size_t ws_size,
                              hipStream_t stream) {
    const float* images = (const float*)d_in[0];
    float* out = (float*)d_out;
    uint* wire = (uint*)d_ws;            // 1024 blocks x 3072 u32 = 12.6 MB

    glcm_fused<<<NIMG * 16, 256, 0, stream>>>(images, wire);
    feature_out_kernel<<<NIMG, 256, 0, stream>>>(wire, out);
}